// Round 5
// baseline (898.498 us; speedup 1.0000x reference)
//
#include <hip/hip_runtime.h>
#include <hip/hip_bf16.h>
#include <math.h>

#define B_ 2
#define T_ 8
#define M_ 512
#define D_ 1024
#define H_ 1024
#define NC_ 1536
#define KNN 8

typedef __hip_bfloat16 bf16;
typedef short v8s __attribute__((ext_vector_type(8)));   // 8 bf16 (4 VGPRs)
typedef float v4f __attribute__((ext_vector_type(4)));   // MFMA acc

__device__ __forceinline__ float b2f(short s) {
  union { unsigned u; float f; } x; x.u = ((unsigned)(unsigned short)s) << 16; return x.f;
}
__device__ __forceinline__ short f2b(float f) {
  bf16 h = __float2bfloat16(f); return *(short*)&h;
}

// ---------------- async global->LDS 16B (wave-uniform base + lane*16 layout)
__device__ __forceinline__ void async16(const void* g, void* l) {
  __builtin_amdgcn_global_load_lds(
      (const __attribute__((address_space(1))) void*)g,
      (__attribute__((address_space(3))) void*)l, 16, 0, 0);
}

// ---------------- bf16 MFMA tile core: acc += A(128xK) * B(128xK)^T
// LDS tile row-major [128][32] bf16, 16B chunks XOR-swizzled.
__device__ __forceinline__ void mfma_loop(const bf16* __restrict__ A,
                                          const bf16* __restrict__ Bp,
                                          int K, v4f (&acc)[4][4],
                                          bf16* sA, bf16* sB)
{
  const int tid  = threadIdx.x;
  const int lane = tid & 63;
  const int wave = tid >> 6;
  const int quad = lane >> 4;
  const int l15  = lane & 15;
  const int wr = (wave >> 1) * 64;
  const int wc = (wave & 1) * 64;

  const int r0 = tid >> 2, g0 = (tid & 3) ^ ((r0 >> 1) & 3);
  const int c1 = tid + 256;
  const int r1 = c1 >> 2,  g1 = (c1 & 3) ^ ((r1 >> 1) & 3);

  const bf16* a0p = A  + (size_t)r0*K + g0*8;
  const bf16* a1p = A  + (size_t)r1*K + g1*8;
  const bf16* b0p = Bp + (size_t)r0*K + g0*8;
  const bf16* b1p = Bp + (size_t)r1*K + g1*8;
  bf16* la0 = sA + tid*8;  bf16* la1 = sA + c1*8;
  bf16* lb0 = sB + tid*8;  bf16* lb1 = sB + c1*8;

  int aoff[4], boff[4];
  #pragma unroll
  for (int i = 0; i < 4; ++i) {
    int ra = wr + i*16 + l15;
    aoff[i] = (ra*4 + (quad ^ ((ra >> 1) & 3))) * 8;
    int rb = wc + i*16 + l15;
    boff[i] = (rb*4 + (quad ^ ((rb >> 1) & 3))) * 8;
  }

  for (int k0 = 0; k0 < K; k0 += 32) {
    __syncthreads();
    async16(a0p + k0, la0);
    async16(a1p + k0, la1);
    async16(b0p + k0, lb0);
    async16(b1p + k0, lb1);
    __syncthreads();
    v8s af[4], bfr[4];
    #pragma unroll
    for (int i = 0; i < 4; ++i) af[i]  = *(const v8s*)(sA + aoff[i]);
    #pragma unroll
    for (int i = 0; i < 4; ++i) bfr[i] = *(const v8s*)(sB + boff[i]);
    #pragma unroll
    for (int mi = 0; mi < 4; ++mi)
      #pragma unroll
      for (int ni = 0; ni < 4; ++ni)
        acc[mi][ni] = __builtin_amdgcn_mfma_f32_16x16x32_bf16(
            af[mi], bfr[ni], acc[mi][ni], 0, 0, 0);
  }
}

// C = A1@B1^T (+A2@B2^T) (+bias) (+add); STATS: emit per-row sum/sumsq partials
template<bool DUAL, bool HASBIAS, bool HASADD, bool OUTBF, bool STATS>
__global__ __launch_bounds__(256) void k_bgemm(
    const bf16* __restrict__ A1, const bf16* __restrict__ B1,
    const bf16* __restrict__ A2, const bf16* __restrict__ B2,
    const float* __restrict__ bias, const float* __restrict__ add,
    void* __restrict__ Cv, int N, int K,
    float* __restrict__ ssum, float* __restrict__ ssq)
{
  __shared__ bf16 sA[128*32];
  __shared__ bf16 sB[128*32];
  v4f acc[4][4];
  #pragma unroll
  for (int i = 0; i < 4; ++i)
    #pragma unroll
    for (int j = 0; j < 4; ++j) acc[i][j] = (v4f){0.f,0.f,0.f,0.f};

  const int row0 = blockIdx.y * 128, col0 = blockIdx.x * 128;
  mfma_loop(A1 + (size_t)row0*K, B1 + (size_t)col0*K, K, acc, sA, sB);
  if constexpr (DUAL)
    mfma_loop(A2 + (size_t)row0*K, B2 + (size_t)col0*K, K, acc, sA, sB);

  const int tid = threadIdx.x, lane = tid & 63, wave = tid >> 6;
  const int quad = lane >> 4, l15 = lane & 15;
  const int wr = (wave >> 1) * 64, wc = (wave & 1) * 64;

  float st_s[4][4], st_q[4][4];
  if constexpr (STATS) {
    #pragma unroll
    for (int a = 0; a < 4; ++a)
      #pragma unroll
      for (int b = 0; b < 4; ++b) { st_s[a][b] = 0.f; st_q[a][b] = 0.f; }
  }

  #pragma unroll
  for (int ni = 0; ni < 4; ++ni) {
    const int col = col0 + wc + ni*16 + l15;
    float bv = 0.f;
    if constexpr (HASBIAS) bv = bias[col];
    #pragma unroll
    for (int mi = 0; mi < 4; ++mi) {
      const int rowb = row0 + wr + mi*16 + quad*4;
      #pragma unroll
      for (int reg = 0; reg < 4; ++reg) {
        const int row = rowb + reg;
        float v = acc[mi][ni][reg] + bv;
        if constexpr (HASADD) v += add[(size_t)row*N + col];
        if constexpr (STATS) { st_s[mi][reg] += v; st_q[mi][reg] += v*v; }
        if constexpr (OUTBF)
          ((bf16*)Cv)[(size_t)row*N + col] = __float2bfloat16(v);
        else
          ((float*)Cv)[(size_t)row*N + col] = v;
      }
    }
  }

  if constexpr (STATS) {
    const int p = blockIdx.x*2 + (wave & 1);
    #pragma unroll
    for (int mi = 0; mi < 4; ++mi)
      #pragma unroll
      for (int reg = 0; reg < 4; ++reg) {
        float s = st_s[mi][reg], q = st_q[mi][reg];
        #pragma unroll
        for (int o = 1; o < 16; o <<= 1) {
          s += __shfl_xor(s, o, 64);
          q += __shfl_xor(q, o, 64);
        }
        if (l15 == 0) {
          const int row = row0 + wr + mi*16 + quad*4 + reg;
          ssum[(size_t)p*8192 + row] = s;
          ssq [(size_t)p*8192 + row] = q;
        }
      }
  }
}

// INP GEMM with LN folded: C = bf16( rstd_r*(Xb@Bw^T) - mu_r*rstd_r*u_j + v_j )
__global__ __launch_bounds__(256) void k_inp(
    const bf16* __restrict__ Xb, const bf16* __restrict__ Bw,
    const float* __restrict__ ssum, const float* __restrict__ ssq,
    const float* __restrict__ u, const float* __restrict__ vv,
    bf16* __restrict__ Cv)
{
  __shared__ bf16 sA[128*32];
  __shared__ bf16 sB[128*32];
  __shared__ float smu[128], srs[128];
  const int row0 = blockIdx.y * 128, col0 = blockIdx.x * 128;
  const int tid = threadIdx.x;
  if (tid < 128) {
    int r = row0 + tid;
    float s = 0.f, q = 0.f;
    #pragma unroll
    for (int p = 0; p < 16; ++p) { s += ssum[(size_t)p*8192 + r]; q += ssq[(size_t)p*8192 + r]; }
    float mu = s * (1.f/D_);
    float var = q * (1.f/D_) - mu*mu;
    smu[tid] = mu; srs[tid] = rsqrtf(var + 1e-5f);
  }
  __syncthreads();

  v4f acc[4][4];
  #pragma unroll
  for (int i = 0; i < 4; ++i)
    #pragma unroll
    for (int j = 0; j < 4; ++j) acc[i][j] = (v4f){0.f,0.f,0.f,0.f};
  mfma_loop(Xb + (size_t)row0*D_, Bw + (size_t)col0*D_, D_, acc, sA, sB);

  const int lane = tid & 63, wave = tid >> 6;
  const int quad = lane >> 4, l15 = lane & 15;
  const int wr = (wave >> 1) * 64, wc = (wave & 1) * 64;
  #pragma unroll
  for (int ni = 0; ni < 4; ++ni) {
    const int col = col0 + wc + ni*16 + l15;
    const float uj = u[col], vj = vv[col];
    #pragma unroll
    for (int mi = 0; mi < 4; ++mi) {
      const int rl = wr + mi*16 + quad*4;
      #pragma unroll
      for (int reg = 0; reg < 4; ++reg) {
        const float mu = smu[rl+reg], rs = srs[rl+reg];
        float v = rs*acc[mi][ni][reg] - mu*rs*uj + vj;
        Cv[(size_t)(row0+rl+reg)*D_ + col] = __float2bfloat16(v);
      }
    }
  }
}

// ---------------- split-bf16 sim (+kh role on z>=48): sim = hi*hi + hi*lo + lo*hi
__global__ __launch_bounds__(256) void k_sims(const bf16* __restrict__ znhi,
                                              const bf16* __restrict__ znlo,
                                              const float* __restrict__ z,
                                              const float* __restrict__ wks,
                                              float* __restrict__ sim,
                                              float* __restrict__ kh)
{
  __shared__ bf16 sAh[128*32];
  __shared__ bf16 sAl[128*32];
  __shared__ bf16 sBh[128*32];
  __shared__ bf16 sBl[128*32];

  const int zi = blockIdx.z;
  const int tid  = threadIdx.x;
  const int lane = tid & 63;
  const int wave = tid >> 6;

  if (zi >= 48) {            // kh role: kh[r] = z[r] . wks, one row per wave
    int kid = (zi - 48)*16 + blockIdx.y*4 + blockIdx.x;
    int r = kid*4 + wave;
    const float* zp = z + (size_t)r*D_ + lane*16;
    const float* wp = wks + lane*16;
    float p = 0.f;
    #pragma unroll
    for (int j = 0; j < 4; ++j) {
      float4 a = *(const float4*)(zp + j*4);
      float4 b = *(const float4*)(wp + j*4);
      p += a.x*b.x + a.y*b.y + a.z*b.z + a.w*b.w;
    }
    for (int o = 32; o; o >>= 1) p += __shfl_down(p, o, 64);
    if (lane == 0) kh[r] = p;
    return;
  }

  const int w  = zi % 3;
  const int bt = zi / 3;
  const int b  = bt / T_;
  const int t  = bt % T_;
  if (w > t) return;                       // masked region — never read by topk
  const int tw = t - w;
  const int arow0 = bt*M_ + blockIdx.y*128;
  const int brow0 = (b*T_ + tw)*M_ + blockIdx.x*128;

  const bf16* Ah = znhi + (size_t)arow0*D_;
  const bf16* Al = znlo + (size_t)arow0*D_;
  const bf16* Bh = znhi + (size_t)brow0*D_;
  const bf16* Bl = znlo + (size_t)brow0*D_;

  v4f acc[4][4];
  #pragma unroll
  for (int i = 0; i < 4; ++i)
    #pragma unroll
    for (int j = 0; j < 4; ++j) acc[i][j] = (v4f){0.f,0.f,0.f,0.f};

  const int quad = lane >> 4;
  const int l15  = lane & 15;
  const int wr = (wave >> 1) * 64;
  const int wc = (wave & 1) * 64;

  const int r0 = tid >> 2, g0 = (tid & 3) ^ ((r0 >> 1) & 3);
  const int c1 = tid + 256;
  const int r1 = c1 >> 2,  g1 = (c1 & 3) ^ ((r1 >> 1) & 3);
  const size_t o0 = (size_t)r0*D_ + g0*8;
  const size_t o1 = (size_t)r1*D_ + g1*8;

  int aoff[4], boff[4];
  #pragma unroll
  for (int i = 0; i < 4; ++i) {
    int ra = wr + i*16 + l15;
    aoff[i] = (ra*4 + (quad ^ ((ra >> 1) & 3))) * 8;
    int rb = wc + i*16 + l15;
    boff[i] = (rb*4 + (quad ^ ((rb >> 1) & 3))) * 8;
  }

  for (int k0 = 0; k0 < D_; k0 += 32) {
    __syncthreads();
    async16(Ah + o0 + k0, sAh + tid*8);
    async16(Ah + o1 + k0, sAh + c1*8);
    async16(Al + o0 + k0, sAl + tid*8);
    async16(Al + o1 + k0, sAl + c1*8);
    async16(Bh + o0 + k0, sBh + tid*8);
    async16(Bh + o1 + k0, sBh + c1*8);
    async16(Bl + o0 + k0, sBl + tid*8);
    async16(Bl + o1 + k0, sBl + c1*8);
    __syncthreads();
    v8s ah[4], al[4], bh[4], bl[4];
    #pragma unroll
    for (int i = 0; i < 4; ++i) {
      ah[i] = *(const v8s*)(sAh + aoff[i]);
      al[i] = *(const v8s*)(sAl + aoff[i]);
      bh[i] = *(const v8s*)(sBh + boff[i]);
      bl[i] = *(const v8s*)(sBl + boff[i]);
    }
    #pragma unroll
    for (int mi = 0; mi < 4; ++mi)
      #pragma unroll
      for (int ni = 0; ni < 4; ++ni) {
        acc[mi][ni] = __builtin_amdgcn_mfma_f32_16x16x32_bf16(ah[mi], bh[ni], acc[mi][ni], 0, 0, 0);
        acc[mi][ni] = __builtin_amdgcn_mfma_f32_16x16x32_bf16(ah[mi], bl[ni], acc[mi][ni], 0, 0, 0);
        acc[mi][ni] = __builtin_amdgcn_mfma_f32_16x16x32_bf16(al[mi], bh[ni], acc[mi][ni], 0, 0, 0);
      }
  }

  float* C = sim + (size_t)bt*M_*NC_;
  const int rowbase = blockIdx.y*128 + wr;
  const int colbase = w*M_ + blockIdx.x*128 + wc;
  #pragma unroll
  for (int ni = 0; ni < 4; ++ni) {
    const int col = colbase + ni*16 + l15;
    #pragma unroll
    for (int mi = 0; mi < 4; ++mi) {
      const int rowb = rowbase + mi*16 + quad*4;
      #pragma unroll
      for (int reg = 0; reg < 4; ++reg)
        C[(size_t)(rowb+reg)*NC_ + col] = acc[mi][ni][reg];
    }
  }
}

// ---------------- persistent 8-step GRU: 256 blocks = 16 rowgrp x 16 colblk,
// tile 64 rows x 64 h-cols x 3 gates; fp32 mem state in registers; row-group
// barriers via device-scope atomics (mem slices exchanged as bf16 ping-pong).
__global__ __launch_bounds__(256, 1) void k_fgrup(
    const bf16* __restrict__ Whhb, const bf16* __restrict__ gib,
    const float* __restrict__ b_hh,
    bf16* __restrict__ mA, bf16* __restrict__ mB,
    bf16* __restrict__ memhb, float* __restrict__ outT,
    unsigned int* __restrict__ ctr)
{
  __shared__ bf16 sA[64*32];
  __shared__ bf16 sB[3][64*32];

  const int colblk = blockIdx.x;           // 16
  const int rg     = blockIdx.y;           // 16 row-groups
  const int row0 = rg*64, col0 = colblk*64;

  const int tid  = threadIdx.x;
  const int lane = tid & 63;
  const int wave = tid >> 6;
  const int quad = lane >> 4;
  const int l15  = lane & 15;
  const int wr   = (wave >> 1) * 32;       // 2 mi tiles
  const int wcol = (wave & 1) * 32;        // 2 ni tiles

  const int rA = tid >> 2, gA = (tid & 3) ^ ((rA >> 1) & 3);
  const size_t aofs = (size_t)rA*H_ + gA*8;                 // + prev_base(row0)
  const size_t bofs = (size_t)(col0 + rA)*H_ + gA*8;        // per gate + g*1M

  int aoff[2], boff[2];
  #pragma unroll
  for (int i = 0; i < 2; ++i) {
    int ra = wr + i*16 + l15;
    aoff[i] = (ra*4 + (quad ^ ((ra >> 1) & 3))) * 8;
    int rb = wcol + i*16 + l15;
    boff[i] = (rb*4 + (quad ^ ((rb >> 1) & 3))) * 8;
  }

  float bhr[2], bhz[2], bhn[2];
  #pragma unroll
  for (int ni = 0; ni < 2; ++ni) {
    const int col = col0 + wcol + ni*16 + l15;
    bhr[ni] = b_hh[col];
    bhz[ni] = b_hh[H_ + col];
    bhn[ni] = b_hh[2*H_ + col];
  }

  float macc[2][2][4];                     // fp32 mem state (row-tile x col-tile)
  #pragma unroll
  for (int mi = 0; mi < 2; ++mi)
    #pragma unroll
    for (int ni = 0; ni < 2; ++ni)
      #pragma unroll
      for (int reg = 0; reg < 4; ++reg) macc[mi][ni][reg] = 0.f;

  for (int t = 0; t < T_; ++t) {
    v4f acc[3][2][2];
    #pragma unroll
    for (int g = 0; g < 3; ++g)
      #pragma unroll
      for (int i = 0; i < 2; ++i)
        #pragma unroll
        for (int j = 0; j < 2; ++j) acc[g][i][j] = (v4f){0.f,0.f,0.f,0.f};

    if (t > 0) {
      const bf16* prev = ((t & 1) ? mA : mB) + (size_t)row0*H_;
      for (int k0 = 0; k0 < H_; k0 += 32) {
        __syncthreads();
        async16(prev + aofs + k0, sA + tid*8);
        async16(Whhb + bofs + k0,           sB[0] + tid*8);
        async16(Whhb + 1048576 + bofs + k0, sB[1] + tid*8);
        async16(Whhb + 2097152 + bofs + k0, sB[2] + tid*8);
        __syncthreads();
        v8s af[2], bfr[3][2];
        #pragma unroll
        for (int i = 0; i < 2; ++i) af[i] = *(const v8s*)(sA + aoff[i]);
        #pragma unroll
        for (int g = 0; g < 3; ++g)
          #pragma unroll
          for (int i = 0; i < 2; ++i) bfr[g][i] = *(const v8s*)(sB[g] + boff[i]);
        #pragma unroll
        for (int g = 0; g < 3; ++g)
          #pragma unroll
          for (int mi = 0; mi < 2; ++mi)
            #pragma unroll
            for (int ni = 0; ni < 2; ++ni)
              acc[g][mi][ni] = __builtin_amdgcn_mfma_f32_16x16x32_bf16(
                  af[mi], bfr[g][ni], acc[g][mi][ni], 0, 0, 0);
      }
    }

    bf16* mcur = (t & 1) ? mB : mA;
    #pragma unroll
    for (int ni = 0; ni < 2; ++ni) {
      const int col = col0 + wcol + ni*16 + l15;
      #pragma unroll
      for (int mi = 0; mi < 2; ++mi) {
        const int rowb = row0 + wr + mi*16 + quad*4;
        #pragma unroll
        for (int reg = 0; reg < 4; ++reg) {
          const int row = rowb + reg;             // b*512 + m
          const int b = row >> 9, m = row & 511;
          const size_t btm = (size_t)((b*T_ + t)*M_ + m);
          const bf16* gp = gib + btm*(3*H_);
          float ir  = b2f(*(const short*)(gp + col));
          float iz  = b2f(*(const short*)(gp + H_ + col));
          float inn = b2f(*(const short*)(gp + 2*H_ + col));
          float hr = acc[0][mi][ni][reg] + bhr[ni];
          float hz = acc[1][mi][ni][reg] + bhz[ni];
          float hn = acc[2][mi][ni][reg] + bhn[ni];
          float rgt = 1.f/(1.f + expf(-(ir + hr)));
          float zgt = 1.f/(1.f + expf(-(iz + hz)));
          float n   = tanhf(inn + rgt*hn);
          float mnew = (1.f - zgt)*n + zgt*macc[mi][ni][reg];
          macc[mi][ni][reg] = mnew;
          bf16 mb = __float2bfloat16(mnew);
          mcur[(size_t)row*H_ + col] = mb;
          memhb[btm*H_ + col] = mb;
          if (t == T_-1) outT[(size_t)row*H_ + col] = mnew;
        }
      }
    }

    if (t < T_-1) {                      // row-group barrier before next step
      __threadfence();
      __syncthreads();
      if (tid == 0) {
        __hip_atomic_fetch_add(&ctr[rg], 1u, __ATOMIC_RELEASE, __HIP_MEMORY_SCOPE_AGENT);
        const unsigned target = 16u*(unsigned)(t+1);
        while (__hip_atomic_load(&ctr[rg], __ATOMIC_ACQUIRE, __HIP_MEMORY_SCOPE_AGENT) < target)
          __builtin_amdgcn_s_sleep(2);
      }
      __syncthreads();
    }
  }
}

// ---------------- mega prep kernel (role-switch on blockIdx.x)
//  [0,10240)      : cast 6 weight mats -> bf16 (Wout scaled by ln_w)
//  [10240,10368)  : colsum(Watt_k) partial + fp32 atomicAdd into wks
//  [10368,10624)  : u_j = ln_w.Wout[j,:], v_j = ln_b.Wout[j,:]  (4 j per block)
//  [10624,10640)  : s0[bt] = z[b,t,0,:] . Watt_q[0,:]
//  [10640,18832)  : per z-row: cast->zb, normalize+split->znhi/znlo
__global__ __launch_bounds__(256) void k_prep(
    const float* __restrict__ Wq, const float* __restrict__ Wv,
    const float* __restrict__ Wout, const float* __restrict__ Wih,
    const float* __restrict__ Whh, const float* __restrict__ Wmf,
    const float* __restrict__ lnw, const float* __restrict__ lnb,
    const float* __restrict__ Wattk, const float* __restrict__ Wattq,
    const float* __restrict__ z,
    bf16* __restrict__ Wdst, float* __restrict__ wks,
    float* __restrict__ u, float* __restrict__ vv, float* __restrict__ s0,
    bf16* __restrict__ zb, bf16* __restrict__ znhi, bf16* __restrict__ znlo)
{
  __shared__ float ps[4], pk[4];
  const int bid = blockIdx.x, tid = threadIdx.x;

  if (bid < 10240) {                       // weight casts
    int i = bid*256 + tid;                 // float4 index
    const float* src; int base;
    if      (i <  262144) { src = Wq;   base = 0; }
    else if (i <  524288) { src = Wv;   base = 262144; }
    else if (i <  786432) { src = Wout; base = 524288; }
    else if (i < 1572864) { src = Wih;  base = 786432; }
    else if (i < 2359296) { src = Whh;  base = 1572864; }
    else                  { src = Wmf;  base = 2359296; }
    float4 v = ((const float4*)src)[i - base];
    if (i >= 524288 && i < 786432) {       // fold ln_w into Wout columns
      int d = (i*4) & 1023;
      float4 w = *(const float4*)(lnw + d);
      v.x *= w.x; v.y *= w.y; v.z *= w.z; v.w *= w.w;
    }
    *(short4*)(Wdst + (size_t)i*4) = make_short4(f2b(v.x), f2b(v.y), f2b(v.z), f2b(v.w));
  } else if (bid < 10368) {                // colsum partial -> atomicAdd
    int rc = bid - 10240;
    int rowc = rc >> 2, colc = rc & 3;
    int d = colc*256 + tid;
    float s = 0.f;
    for (int r = rowc*32; r < rowc*32 + 32; ++r) s += Wattk[(size_t)r*D_ + d];
    atomicAdd(&wks[d], s);
  } else if (bid < 10624) {                // u,v rows (1 j per wave)
    int j = (bid - 10368)*4 + (tid >> 6);
    int l = tid & 63;
    const float* wr_ = Wout + (size_t)j*D_ + l*16;
    const float* aw = lnw + l*16;
    const float* ab = lnb + l*16;
    float pu = 0.f, pv = 0.f;
    #pragma unroll
    for (int q = 0; q < 4; ++q) {
      float4 a = *(const float4*)(wr_ + q*4);
      float4 x = *(const float4*)(aw + q*4);
      float4 y = *(const float4*)(ab + q*4);
      pu += a.x*x.x + a.y*x.y + a.z*x.z + a.w*x.w;
      pv += a.x*y.x + a.y*y.y + a.z*y.z + a.w*y.w;
    }
    for (int o = 32; o; o >>= 1) { pu += __shfl_down(pu, o, 64); pv += __shfl_down(pv, o, 64); }
    if (l == 0) { u[j] = pu; vv[j] = pv; }
  } else if (bid < 10640) {                // s0
    int bt = bid - 10624;
    int d = tid*4;
    float4 a = *(const float4*)(z + (size_t)bt*M_*D_ + d);
    float4 q = *(const float4*)(Wattq + d);
    float p = a.x*q.x + a.y*q.y + a.z*q.z + a.w*q.w;
    for (int o = 32; o; o >>= 1) p += __shfl_down(p, o, 64);
    if ((tid & 63) == 0) ps[tid >> 6] = p;
    __syncthreads();
    if (tid == 0) s0[bt] = ps[0]+ps[1]+ps[2]+ps[3];
  } else {                                 // zprep
    int row = bid - 10640;
    const float* zr = z + (size_t)row*D_;
    int d = tid*4;
    float4 v = *(const float4*)(zr + d);
    float ss = v.x*v.x + v.y*v.y + v.z*v.z + v.w*v.w;
    for (int o = 32; o; o >>= 1) ss += __shfl_down(ss, o, 64);
    if ((tid & 63) == 0) pk[tid >> 6] = ss;
    __syncthreads();
    float s = pk[0]+pk[1]+pk[2]+pk[3];
    float rn = 1.0f / fmaxf(sqrtf(s), 1e-12f);
    *(short4*)(zb + (size_t)row*D_ + d) = make_short4(f2b(v.x), f2b(v.y), f2b(v.z), f2b(v.w));
    float zn[4] = {v.x*rn, v.y*rn, v.z*rn, v.w*rn};
    short hi[4], lo[4];
    #pragma unroll
    for (int j = 0; j < 4; ++j) {
      hi[j] = f2b(zn[j]);
      lo[j] = f2b(zn[j] - b2f(hi[j]));
    }
    *(short4*)(znhi + (size_t)row*D_ + d) = make_short4(hi[0],hi[1],hi[2],hi[3]);
    *(short4*)(znlo + (size_t)row*D_ + d) = make_short4(lo[0],lo[1],lo[2],lo[3]);
  }
}

// wave-per-row: top-8 -> att softmax -> alpha -> kbar(bf16) = sum alpha_k z_k
__global__ __launch_bounds__(256) void k_topk(
    const float* __restrict__ sim, const float* __restrict__ kh,
    const float* __restrict__ s0, const bf16* __restrict__ zb,
    bf16* __restrict__ kbarb)
{
  const int wave = threadIdx.x >> 6, l = threadIdx.x & 63;
  const int r  = blockIdx.x*4 + wave;
  const int bt = r >> 9, m = r & 511;
  const int b  = bt >> 3, t = bt & 7;
  const float* srow = sim + (size_t)bt*M_*NC_ + (size_t)m*NC_;
  const int limit = (t >= 2) ? NC_ : ((t == 1) ? 2*M_ : M_);

  float v[24];
  #pragma unroll
  for (int j = 0; j < 24; ++j) {
    int i = j*64 + l;
    v[j] = (i < limit) ? srow[i] : -INFINITY;
  }

  float selv[KNN]; int seli[KNN];
  #pragma unroll
  for (int k = 0; k < KNN; ++k) {
    float bv = v[0]; int bj = 0;
    #pragma unroll
    for (int j = 1; j < 24; ++j)
      if (v[j] > bv) { bv = v[j]; bj = j; }
    int bi = bj*64 + l;
    #pragma unroll
    for (int o = 1; o < 64; o <<= 1) {
      float ov = __shfl_xor(bv, o, 64);
      int   oi = __shfl_xor(bi, o, 64);
      if (ov > bv || (ov == bv && oi < bi)) { bv = ov; bi = oi; }
    }
    selv[k] = bv; seli[k] = bi;
    if ((bi & 63) == l) {
      int jj = bi >> 6;
      #pragma unroll
      for (int j = 0; j < 24; ++j) if (j == jj) v[j] = -INFINITY;
    }
  }

  float khv = 0.f;
  if (l < KNN) {
    int idx = seli[l];
    int w = idx >> 9, n = idx & 511;
    int tt = t - w;
    khv = kh[(b*T_ + tt)*M_ + n];
  }
  float s0v = s0[bt];
  float att[KNN], mx = -INFINITY;
  #pragma unroll
  for (int k = 0; k < KNN; ++k) { att[k] = s0v * __shfl(khv, k, 64); mx = fmaxf(mx, att[k]); }
  float den = 0.f;
  #pragma unroll
  for (int k = 0; k < KNN; ++k) { att[k] = expf(att[k]-mx); den += att[k]; }
  float rden = 1.0f/den;
  float alpha[KNN];
  #pragma unroll
  for (int k = 0; k < KNN; ++k) alpha[k] = 0.5f*selv[k] + 0.5f*att[k]*rden;

  const int d0 = l*16;
  float o[16];
  #pragma unroll
  for (int e = 0; e < 16; ++e) o[e] = 0.f;
  #pragma unroll
  for (int k = 0; k < KNN; ++k) {
    int idx = seli[k];
    int w = idx >> 9, n = idx & 511;
    int tt = t - w;
    const bf16* zp = zb + ((size_t)((b*T_ + tt)*M_ + n))*D_ + d0;
    v8s z0 = *(const v8s*)zp;
    v8s z1 = *(const v8s*)(zp + 8);
    float al = alpha[k];
    #pragma unroll
    for (int e = 0; e < 8; ++e) {
      o[e]   = fmaf(al, b2f(z0[e]), o[e]);
      o[8+e] = fmaf(al, b2f(z1[e]), o[8+e]);
    }
  }
  bf16* kp = kbarb + (size_t)r*D_ + d0;
  short outv[16];
  #pragma unroll
  for (int e = 0; e < 16; ++e) outv[e] = f2b(o[e]);
  *(v8s*)kp       = *(v8s*)outv;
  *(v8s*)(kp + 8) = *(v8s*)(outv + 8);
}

extern "C" void kernel_launch(void* const* d_in, const int* in_sizes, int n_in,
                              void* d_out, int out_size, void* d_ws, size_t ws_size,
                              hipStream_t stream) {
  (void)in_sizes; (void)n_in; (void)out_size; (void)ws_size;
  const float* z      = (const float*)d_in[0];
  const float* Wq     = (const float*)d_in[1];
  const float* Wv     = (const float*)d_in[2];
  const float* Wout   = (const float*)d_in[3];
  const float* ln_w   = (const float*)d_in[4];
  const float* ln_b   = (const float*)d_in[5];
  const float* Watt_q = (const float*)d_in[6];
  const float* Watt_k = (const float*)d_in[7];
  const float* W_ih   = (const float*)d_in[8];
  const float* W_hh   = (const float*)d_in[9];
  const float* b_ih   = (const float*)d_in[10];
  const float* b_hh   = (const float*)d_in[11];
  const float* W_mf   = (const float*)d_in[12];
  const float* b_mf   = (const float*)d_in[13];
  float* out = (float*)d_out;
  float* ws  = (float*)d_ws;

  // workspace layout (float offsets)
  float* sim   = ws;                          // 12,582,912 f ; GIb aliases
  bf16*  GIb   = (bf16*)ws;
  bf16*  znhi  = (bf16*)(ws + 12582912);      // 8,388,608 bf16 ; Xb aliases
  bf16*  Xb    = znhi;
  bf16*  zb    = (bf16*)(ws + 16777216);      // 8,388,608 bf16
  bf16*  kbarb = (bf16*)(ws + 20971520);      // 8,388,608 bf16 ; INPb aliases
  bf16*  INPb  = kbarb;
  bf16*  memhb = (bf16*)(ws + 25165824);      // 8,388,608 bf16 ; znlo aliases
  bf16*  znlo  = memhb;
  bf16*  mA    = (bf16*)(ws + 29360128);      // 1,048,576 bf16
  bf16*  mB    = (bf16*)(ws + 29884416);      // 1,048,576 bf16
  bf16*  Wqb   = (bf16*)(ws + 30408704);      // 10,485,760 bf16 contiguous
  bf16*  Wvb   = Wqb + 1048576;
  bf16*  Woutb = Wqb + 2097152;               // scaled by ln_w
  bf16*  Wihb  = Wqb + 3145728;
  bf16*  Whhb  = Wqb + 6291456;
  bf16*  Wmfb  = Wqb + 9437184;
  float* wks   = ws + 35651584;               // 1024
  unsigned int* ctr = (unsigned int*)(ws + 35652608);   // 16 (+pad)
  float* s0    = ws + 35652640;               // 16
  float* kh    = ws + 35652656;               // 8192
  float* u     = ws + 35660848;               // 1024
  float* vv    = ws + 35661872;               // 1024
  float* ssum  = ws + 35662896;               // 16*8192
  float* ssq   = ws + 35793968;               // 16*8192
  // end 35,925,040 floats ~ 137 MiB

  // 1. zero wks + ctr (wks..ctr contiguous: 1024 f + 32 f)
  hipMemsetAsync(wks, 0, (1024 + 32)*sizeof(float), stream);

  // 2. mega-prep
  k_prep<<<dim3(18832), dim3(256), 0, stream>>>(
      Wq, Wv, Wout, W_ih, W_hh, W_mf, ln_w, ln_b, Watt_k, Watt_q, z,
      Wqb, wks, u, vv, s0, zb, znhi, znlo);

  // 3. sim (split-bf16 MFMA) + kh role
  k_sims<<<dim3(4,4,176), dim3(256), 0, stream>>>(znhi, znlo, z, wks, sim, kh);

  // 4. topk + attention + kbar
  k_topk<<<dim3(2048), dim3(256), 0, stream>>>(sim, kh, s0, zb, kbarb);

  // 5. X = kbar@Wv^T + z@Wq^T -> bf16 Xb + LN stats partials
  k_bgemm<true,false,false,true,true><<<dim3(8,64), dim3(256), 0, stream>>>(
      kbarb, Wvb, zb, Wqb, nullptr, nullptr, Xb, D_, D_, ssum, ssq);

  // 6. INP = LN(X)@Wout^T (LN folded) -> bf16
  k_inp<<<dim3(8,64), dim3(256), 0, stream>>>(Xb, Woutb, ssum, ssq, u, vv, INPb);

  // 7. GI = INP@W_ih^T + b_ih -> bf16 (overlays sim)
  k_bgemm<false,true,false,true,false><<<dim3(24,64), dim3(256), 0, stream>>>(
      INPb, Wihb, nullptr, nullptr, b_ih, nullptr, GIb, 3*H_, D_, nullptr, nullptr);

  // 8. persistent 8-step GRU (writes memhb + fp32 mem -> out tail)
  k_fgrup<<<dim3(16,16), dim3(256), 0, stream>>>(
      Whhb, GIb, b_hh, mA, mB, memhb, out + (size_t)B_*T_*M_*D_, ctr);

  // 9. OUT = z + memh@W_mf^T + b_mf
  k_bgemm<false,true,true,false,false><<<dim3(8,64), dim3(256), 0, stream>>>(
      memhb, Wmfb, nullptr, nullptr, b_mf, z, out, D_, H_, nullptr, nullptr);
}

// Round 6
// 671.070 us; speedup vs baseline: 1.3389x; 1.3389x over previous
//
#include <hip/hip_runtime.h>
#include <hip/hip_bf16.h>
#include <math.h>

#define B_ 2
#define T_ 8
#define M_ 512
#define D_ 1024
#define H_ 1024
#define NC_ 1536
#define KNN 8

typedef __hip_bfloat16 bf16;
typedef short v8s __attribute__((ext_vector_type(8)));   // 8 bf16 (4 VGPRs)
typedef float v4f __attribute__((ext_vector_type(4)));   // MFMA acc

__device__ __forceinline__ float b2f(short s) {
  union { unsigned u; float f; } x; x.u = ((unsigned)(unsigned short)s) << 16; return x.f;
}
__device__ __forceinline__ short f2b(float f) {
  bf16 h = __float2bfloat16(f); return *(short*)&h;
}

// ---------------- async global->LDS 16B (wave-uniform base + lane*16 layout)
__device__ __forceinline__ void async16(const void* g, void* l) {
  __builtin_amdgcn_global_load_lds(
      (const __attribute__((address_space(1))) void*)g,
      (__attribute__((address_space(3))) void*)l, 16, 0, 0);
}

// ---------------- bf16 MFMA tile core: acc += A(128xK) * B(128xK)^T
// LDS tile row-major [128][32] bf16, 16B chunks XOR-swizzled.
__device__ __forceinline__ void mfma_loop(const bf16* __restrict__ A,
                                          const bf16* __restrict__ Bp,
                                          int K, v4f (&acc)[4][4],
                                          bf16* sA, bf16* sB)
{
  const int tid  = threadIdx.x;
  const int lane = tid & 63;
  const int wave = tid >> 6;
  const int quad = lane >> 4;
  const int l15  = lane & 15;
  const int wr = (wave >> 1) * 64;
  const int wc = (wave & 1) * 64;

  const int r0 = tid >> 2, g0 = (tid & 3) ^ ((r0 >> 1) & 3);
  const int c1 = tid + 256;
  const int r1 = c1 >> 2,  g1 = (c1 & 3) ^ ((r1 >> 1) & 3);

  const bf16* a0p = A  + (size_t)r0*K + g0*8;
  const bf16* a1p = A  + (size_t)r1*K + g1*8;
  const bf16* b0p = Bp + (size_t)r0*K + g0*8;
  const bf16* b1p = Bp + (size_t)r1*K + g1*8;
  bf16* la0 = sA + tid*8;  bf16* la1 = sA + c1*8;
  bf16* lb0 = sB + tid*8;  bf16* lb1 = sB + c1*8;

  int aoff[4], boff[4];
  #pragma unroll
  for (int i = 0; i < 4; ++i) {
    int ra = wr + i*16 + l15;
    aoff[i] = (ra*4 + (quad ^ ((ra >> 1) & 3))) * 8;
    int rb = wc + i*16 + l15;
    boff[i] = (rb*4 + (quad ^ ((rb >> 1) & 3))) * 8;
  }

  for (int k0 = 0; k0 < K; k0 += 32) {
    __syncthreads();
    async16(a0p + k0, la0);
    async16(a1p + k0, la1);
    async16(b0p + k0, lb0);
    async16(b1p + k0, lb1);
    __syncthreads();
    v8s af[4], bfr[4];
    #pragma unroll
    for (int i = 0; i < 4; ++i) af[i]  = *(const v8s*)(sA + aoff[i]);
    #pragma unroll
    for (int i = 0; i < 4; ++i) bfr[i] = *(const v8s*)(sB + boff[i]);
    #pragma unroll
    for (int mi = 0; mi < 4; ++mi)
      #pragma unroll
      for (int ni = 0; ni < 4; ++ni)
        acc[mi][ni] = __builtin_amdgcn_mfma_f32_16x16x32_bf16(
            af[mi], bfr[ni], acc[mi][ni], 0, 0, 0);
  }
}

// C = A1@B1^T (+A2@B2^T) (+bias) (+add); STATS: emit per-row sum/sumsq partials
template<bool DUAL, bool HASBIAS, bool HASADD, bool OUTBF, bool STATS>
__global__ __launch_bounds__(256) void k_bgemm(
    const bf16* __restrict__ A1, const bf16* __restrict__ B1,
    const bf16* __restrict__ A2, const bf16* __restrict__ B2,
    const float* __restrict__ bias, const float* __restrict__ add,
    void* __restrict__ Cv, int N, int K,
    float* __restrict__ ssum, float* __restrict__ ssq)
{
  __shared__ bf16 sA[128*32];
  __shared__ bf16 sB[128*32];
  v4f acc[4][4];
  #pragma unroll
  for (int i = 0; i < 4; ++i)
    #pragma unroll
    for (int j = 0; j < 4; ++j) acc[i][j] = (v4f){0.f,0.f,0.f,0.f};

  const int row0 = blockIdx.y * 128, col0 = blockIdx.x * 128;
  mfma_loop(A1 + (size_t)row0*K, B1 + (size_t)col0*K, K, acc, sA, sB);
  if constexpr (DUAL)
    mfma_loop(A2 + (size_t)row0*K, B2 + (size_t)col0*K, K, acc, sA, sB);

  const int tid = threadIdx.x, lane = tid & 63, wave = tid >> 6;
  const int quad = lane >> 4, l15 = lane & 15;
  const int wr = (wave >> 1) * 64, wc = (wave & 1) * 64;

  float st_s[4][4], st_q[4][4];
  if constexpr (STATS) {
    #pragma unroll
    for (int a = 0; a < 4; ++a)
      #pragma unroll
      for (int b = 0; b < 4; ++b) { st_s[a][b] = 0.f; st_q[a][b] = 0.f; }
  }

  #pragma unroll
  for (int ni = 0; ni < 4; ++ni) {
    const int col = col0 + wc + ni*16 + l15;
    float bv = 0.f;
    if constexpr (HASBIAS) bv = bias[col];
    #pragma unroll
    for (int mi = 0; mi < 4; ++mi) {
      const int rowb = row0 + wr + mi*16 + quad*4;
      #pragma unroll
      for (int reg = 0; reg < 4; ++reg) {
        const int row = rowb + reg;
        float v = acc[mi][ni][reg] + bv;
        if constexpr (HASADD) v += add[(size_t)row*N + col];
        if constexpr (STATS) { st_s[mi][reg] += v; st_q[mi][reg] += v*v; }
        if constexpr (OUTBF)
          ((bf16*)Cv)[(size_t)row*N + col] = __float2bfloat16(v);
        else
          ((float*)Cv)[(size_t)row*N + col] = v;
      }
    }
  }

  if constexpr (STATS) {
    const int p = blockIdx.x*2 + (wave & 1);
    #pragma unroll
    for (int mi = 0; mi < 4; ++mi)
      #pragma unroll
      for (int reg = 0; reg < 4; ++reg) {
        float s = st_s[mi][reg], q = st_q[mi][reg];
        #pragma unroll
        for (int o = 1; o < 16; o <<= 1) {
          s += __shfl_xor(s, o, 64);
          q += __shfl_xor(q, o, 64);
        }
        if (l15 == 0) {
          const int row = row0 + wr + mi*16 + quad*4 + reg;
          ssum[(size_t)p*8192 + row] = s;
          ssq [(size_t)p*8192 + row] = q;
        }
      }
  }
}

// INP GEMM with LN folded: C = bf16( rstd_r*(Xb@Bw^T) - mu_r*rstd_r*u_j + v_j )
__global__ __launch_bounds__(256) void k_inp(
    const bf16* __restrict__ Xb, const bf16* __restrict__ Bw,
    const float* __restrict__ ssum, const float* __restrict__ ssq,
    const float* __restrict__ u, const float* __restrict__ vv,
    bf16* __restrict__ Cv)
{
  __shared__ bf16 sA[128*32];
  __shared__ bf16 sB[128*32];
  __shared__ float smu[128], srs[128];
  const int row0 = blockIdx.y * 128, col0 = blockIdx.x * 128;
  const int tid = threadIdx.x;
  if (tid < 128) {
    int r = row0 + tid;
    float s = 0.f, q = 0.f;
    #pragma unroll
    for (int p = 0; p < 16; ++p) { s += ssum[(size_t)p*8192 + r]; q += ssq[(size_t)p*8192 + r]; }
    float mu = s * (1.f/D_);
    float var = q * (1.f/D_) - mu*mu;
    smu[tid] = mu; srs[tid] = rsqrtf(var + 1e-5f);
  }
  __syncthreads();

  v4f acc[4][4];
  #pragma unroll
  for (int i = 0; i < 4; ++i)
    #pragma unroll
    for (int j = 0; j < 4; ++j) acc[i][j] = (v4f){0.f,0.f,0.f,0.f};
  mfma_loop(Xb + (size_t)row0*D_, Bw + (size_t)col0*D_, D_, acc, sA, sB);

  const int lane = tid & 63, wave = tid >> 6;
  const int quad = lane >> 4, l15 = lane & 15;
  const int wr = (wave >> 1) * 64, wc = (wave & 1) * 64;
  #pragma unroll
  for (int ni = 0; ni < 4; ++ni) {
    const int col = col0 + wc + ni*16 + l15;
    const float uj = u[col], vj = vv[col];
    #pragma unroll
    for (int mi = 0; mi < 4; ++mi) {
      const int rl = wr + mi*16 + quad*4;
      #pragma unroll
      for (int reg = 0; reg < 4; ++reg) {
        const float mu = smu[rl+reg], rs = srs[rl+reg];
        float v = rs*acc[mi][ni][reg] - mu*rs*uj + vj;
        Cv[(size_t)(row0+rl+reg)*D_ + col] = __float2bfloat16(v);
      }
    }
  }
}

// ---------------- split-bf16 sim (+kh role on z>=48): sim = hi*hi + hi*lo + lo*hi
__global__ __launch_bounds__(256) void k_sims(const bf16* __restrict__ znhi,
                                              const bf16* __restrict__ znlo,
                                              const float* __restrict__ z,
                                              const float* __restrict__ wks,
                                              float* __restrict__ sim,
                                              float* __restrict__ kh)
{
  __shared__ bf16 sAh[128*32];
  __shared__ bf16 sAl[128*32];
  __shared__ bf16 sBh[128*32];
  __shared__ bf16 sBl[128*32];

  const int zi = blockIdx.z;
  const int tid  = threadIdx.x;
  const int lane = tid & 63;
  const int wave = tid >> 6;

  if (zi >= 48) {            // kh role: kh[r] = z[r] . wks, one row per wave
    int kid = (zi - 48)*16 + blockIdx.y*4 + blockIdx.x;
    int r = kid*4 + wave;
    const float* zp = z + (size_t)r*D_ + lane*16;
    const float* wp = wks + lane*16;
    float p = 0.f;
    #pragma unroll
    for (int j = 0; j < 4; ++j) {
      float4 a = *(const float4*)(zp + j*4);
      float4 b = *(const float4*)(wp + j*4);
      p += a.x*b.x + a.y*b.y + a.z*b.z + a.w*b.w;
    }
    for (int o = 32; o; o >>= 1) p += __shfl_down(p, o, 64);
    if (lane == 0) kh[r] = p;
    return;
  }

  const int w  = zi % 3;
  const int bt = zi / 3;
  const int b  = bt / T_;
  const int t  = bt % T_;
  if (w > t) return;                       // masked region — never read by topk
  const int tw = t - w;
  const int arow0 = bt*M_ + blockIdx.y*128;
  const int brow0 = (b*T_ + tw)*M_ + blockIdx.x*128;

  const bf16* Ah = znhi + (size_t)arow0*D_;
  const bf16* Al = znlo + (size_t)arow0*D_;
  const bf16* Bh = znhi + (size_t)brow0*D_;
  const bf16* Bl = znlo + (size_t)brow0*D_;

  v4f acc[4][4];
  #pragma unroll
  for (int i = 0; i < 4; ++i)
    #pragma unroll
    for (int j = 0; j < 4; ++j) acc[i][j] = (v4f){0.f,0.f,0.f,0.f};

  const int quad = lane >> 4;
  const int l15  = lane & 15;
  const int wr = (wave >> 1) * 64;
  const int wc = (wave & 1) * 64;

  const int r0 = tid >> 2, g0 = (tid & 3) ^ ((r0 >> 1) & 3);
  const int c1 = tid + 256;
  const int r1 = c1 >> 2,  g1 = (c1 & 3) ^ ((r1 >> 1) & 3);
  const size_t o0 = (size_t)r0*D_ + g0*8;
  const size_t o1 = (size_t)r1*D_ + g1*8;

  int aoff[4], boff[4];
  #pragma unroll
  for (int i = 0; i < 4; ++i) {
    int ra = wr + i*16 + l15;
    aoff[i] = (ra*4 + (quad ^ ((ra >> 1) & 3))) * 8;
    int rb = wc + i*16 + l15;
    boff[i] = (rb*4 + (quad ^ ((rb >> 1) & 3))) * 8;
  }

  for (int k0 = 0; k0 < D_; k0 += 32) {
    __syncthreads();
    async16(Ah + o0 + k0, sAh + tid*8);
    async16(Ah + o1 + k0, sAh + c1*8);
    async16(Al + o0 + k0, sAl + tid*8);
    async16(Al + o1 + k0, sAl + c1*8);
    async16(Bh + o0 + k0, sBh + tid*8);
    async16(Bh + o1 + k0, sBh + c1*8);
    async16(Bl + o0 + k0, sBl + tid*8);
    async16(Bl + o1 + k0, sBl + c1*8);
    __syncthreads();
    v8s ah[4], al[4], bh[4], bl[4];
    #pragma unroll
    for (int i = 0; i < 4; ++i) {
      ah[i] = *(const v8s*)(sAh + aoff[i]);
      al[i] = *(const v8s*)(sAl + aoff[i]);
      bh[i] = *(const v8s*)(sBh + boff[i]);
      bl[i] = *(const v8s*)(sBl + boff[i]);
    }
    #pragma unroll
    for (int mi = 0; mi < 4; ++mi)
      #pragma unroll
      for (int ni = 0; ni < 4; ++ni) {
        acc[mi][ni] = __builtin_amdgcn_mfma_f32_16x16x32_bf16(ah[mi], bh[ni], acc[mi][ni], 0, 0, 0);
        acc[mi][ni] = __builtin_amdgcn_mfma_f32_16x16x32_bf16(ah[mi], bl[ni], acc[mi][ni], 0, 0, 0);
        acc[mi][ni] = __builtin_amdgcn_mfma_f32_16x16x32_bf16(al[mi], bh[ni], acc[mi][ni], 0, 0, 0);
      }
  }

  float* C = sim + (size_t)bt*M_*NC_;
  const int rowbase = blockIdx.y*128 + wr;
  const int colbase = w*M_ + blockIdx.x*128 + wc;
  #pragma unroll
  for (int ni = 0; ni < 4; ++ni) {
    const int col = colbase + ni*16 + l15;
    #pragma unroll
    for (int mi = 0; mi < 4; ++mi) {
      const int rowb = rowbase + mi*16 + quad*4;
      #pragma unroll
      for (int reg = 0; reg < 4; ++reg)
        C[(size_t)(rowb+reg)*NC_ + col] = acc[mi][ni][reg];
    }
  }
}

// ---------------- per-step fused Whh-GEMM(3 gates) + GRU epilogue
// grid (16,16): 64 mem-rows x 64 h-cols x 3 gates per block; 256 blocks = all CUs
__global__ __launch_bounds__(256) void k_fgru2(
    const bf16* __restrict__ membIn, const bf16* __restrict__ Whhb,
    const bf16* __restrict__ gib, const float* __restrict__ b_hh,
    float* __restrict__ mem, bf16* __restrict__ membOut,
    bf16* __restrict__ memhb, float* __restrict__ outT, int t)
{
  __shared__ bf16 sA[64*32];
  __shared__ bf16 sB[3][64*32];

  const int row0 = blockIdx.y*64, col0 = blockIdx.x*64;

  const int tid  = threadIdx.x;
  const int lane = tid & 63;
  const int wave = tid >> 6;
  const int quad = lane >> 4;
  const int l15  = lane & 15;
  const int wr   = (wave >> 1) * 32;       // 2 mi tiles
  const int wcol = (wave & 1) * 32;        // 2 ni tiles

  const int rA = tid >> 2, gA = (tid & 3) ^ ((rA >> 1) & 3);
  const size_t aofs = (size_t)rA*H_ + gA*8;
  const size_t bofs = (size_t)(col0 + rA)*H_ + gA*8;

  int aoff[2], boff[2];
  #pragma unroll
  for (int i = 0; i < 2; ++i) {
    int ra = wr + i*16 + l15;
    aoff[i] = (ra*4 + (quad ^ ((ra >> 1) & 3))) * 8;
    int rb = wcol + i*16 + l15;
    boff[i] = (rb*4 + (quad ^ ((rb >> 1) & 3))) * 8;
  }

  v4f acc[3][2][2];
  #pragma unroll
  for (int g = 0; g < 3; ++g)
    #pragma unroll
    for (int i = 0; i < 2; ++i)
      #pragma unroll
      for (int j = 0; j < 2; ++j) acc[g][i][j] = (v4f){0.f,0.f,0.f,0.f};

  if (t > 0) {
    const bf16* prev = membIn + (size_t)row0*H_;
    for (int k0 = 0; k0 < H_; k0 += 32) {
      __syncthreads();
      async16(prev + aofs + k0, sA + tid*8);
      async16(Whhb + bofs + k0,           sB[0] + tid*8);
      async16(Whhb + 1048576 + bofs + k0, sB[1] + tid*8);
      async16(Whhb + 2097152 + bofs + k0, sB[2] + tid*8);
      __syncthreads();
      v8s af[2], bfr[3][2];
      #pragma unroll
      for (int i = 0; i < 2; ++i) af[i] = *(const v8s*)(sA + aoff[i]);
      #pragma unroll
      for (int g = 0; g < 3; ++g)
        #pragma unroll
        for (int i = 0; i < 2; ++i) bfr[g][i] = *(const v8s*)(sB[g] + boff[i]);
      #pragma unroll
      for (int g = 0; g < 3; ++g)
        #pragma unroll
        for (int mi = 0; mi < 2; ++mi)
          #pragma unroll
          for (int ni = 0; ni < 2; ++ni)
            acc[g][mi][ni] = __builtin_amdgcn_mfma_f32_16x16x32_bf16(
                af[mi], bfr[g][ni], acc[g][mi][ni], 0, 0, 0);
    }
  }

  #pragma unroll
  for (int ni = 0; ni < 2; ++ni) {
    const int col = col0 + wcol + ni*16 + l15;
    const float bhr = b_hh[col];
    const float bhz = b_hh[H_ + col];
    const float bhn = b_hh[2*H_ + col];
    #pragma unroll
    for (int mi = 0; mi < 2; ++mi) {
      const int rowb = row0 + wr + mi*16 + quad*4;
      #pragma unroll
      for (int reg = 0; reg < 4; ++reg) {
        const int row = rowb + reg;              // b*512 + m
        const int b = row >> 9, m = row & 511;
        const size_t btm = (size_t)((b*T_ + t)*M_ + m);
        const bf16* gp = gib + btm*(3*H_);
        float ir  = b2f(*(const short*)(gp + col));
        float iz  = b2f(*(const short*)(gp + H_ + col));
        float inn = b2f(*(const short*)(gp + 2*H_ + col));
        float hr = acc[0][mi][ni][reg] + bhr;
        float hz = acc[1][mi][ni][reg] + bhz;
        float hn = acc[2][mi][ni][reg] + bhn;
        float rgt = 1.f/(1.f + expf(-(ir + hr)));
        float zgt = 1.f/(1.f + expf(-(iz + hz)));
        float n   = tanhf(inn + rgt*hn);
        const size_t mo = (size_t)row*H_ + col;
        float mold = (t > 0) ? mem[mo] : 0.f;
        float mnew = (1.f - zgt)*n + zgt*mold;
        mem[mo] = mnew;
        bf16 mb = __float2bfloat16(mnew);
        membOut[mo] = mb;
        memhb[btm*H_ + col] = mb;
        if (t == T_-1) outT[mo] = mnew;
      }
    }
  }
}

// ---------------- mega prep kernel (role-switch on blockIdx.x)
//  [0,10240)      : cast 6 weight mats -> bf16 (Wout scaled by ln_w)
//  [10240,10368)  : colsum(Watt_k) partial + fp32 atomicAdd into wks
//  [10368,10624)  : u_j = ln_w.Wout[j,:], v_j = ln_b.Wout[j,:]  (4 j per block)
//  [10624,10640)  : s0[bt] = z[b,t,0,:] . Watt_q[0,:]
//  [10640,18832)  : per z-row: cast->zb, normalize+split->znhi/znlo
__global__ __launch_bounds__(256) void k_prep(
    const float* __restrict__ Wq, const float* __restrict__ Wv,
    const float* __restrict__ Wout, const float* __restrict__ Wih,
    const float* __restrict__ Whh, const float* __restrict__ Wmf,
    const float* __restrict__ lnw, const float* __restrict__ lnb,
    const float* __restrict__ Wattk, const float* __restrict__ Wattq,
    const float* __restrict__ z,
    bf16* __restrict__ Wdst, float* __restrict__ wks,
    float* __restrict__ u, float* __restrict__ vv, float* __restrict__ s0,
    bf16* __restrict__ zb, bf16* __restrict__ znhi, bf16* __restrict__ znlo)
{
  __shared__ float ps[4], pk[4];
  const int bid = blockIdx.x, tid = threadIdx.x;

  if (bid < 10240) {                       // weight casts
    int i = bid*256 + tid;                 // float4 index
    const float* src; int base;
    if      (i <  262144) { src = Wq;   base = 0; }
    else if (i <  524288) { src = Wv;   base = 262144; }
    else if (i <  786432) { src = Wout; base = 524288; }
    else if (i < 1572864) { src = Wih;  base = 786432; }
    else if (i < 2359296) { src = Whh;  base = 1572864; }
    else                  { src = Wmf;  base = 2359296; }
    float4 v = ((const float4*)src)[i - base];
    if (i >= 524288 && i < 786432) {       // fold ln_w into Wout columns
      int d = (i*4) & 1023;
      float4 w = *(const float4*)(lnw + d);
      v.x *= w.x; v.y *= w.y; v.z *= w.z; v.w *= w.w;
    }
    *(short4*)(Wdst + (size_t)i*4) = make_short4(f2b(v.x), f2b(v.y), f2b(v.z), f2b(v.w));
  } else if (bid < 10368) {                // colsum partial -> atomicAdd
    int rc = bid - 10240;
    int rowc = rc >> 2, colc = rc & 3;
    int d = colc*256 + tid;
    float s = 0.f;
    for (int r = rowc*32; r < rowc*32 + 32; ++r) s += Wattk[(size_t)r*D_ + d];
    atomicAdd(&wks[d], s);
  } else if (bid < 10624) {                // u,v rows (1 j per wave)
    int j = (bid - 10368)*4 + (tid >> 6);
    int l = tid & 63;
    const float* wr_ = Wout + (size_t)j*D_ + l*16;
    const float* aw = lnw + l*16;
    const float* ab = lnb + l*16;
    float pu = 0.f, pv = 0.f;
    #pragma unroll
    for (int q = 0; q < 4; ++q) {
      float4 a = *(const float4*)(wr_ + q*4);
      float4 x = *(const float4*)(aw + q*4);
      float4 y = *(const float4*)(ab + q*4);
      pu += a.x*x.x + a.y*x.y + a.z*x.z + a.w*x.w;
      pv += a.x*y.x + a.y*y.y + a.z*y.z + a.w*y.w;
    }
    for (int o = 32; o; o >>= 1) { pu += __shfl_down(pu, o, 64); pv += __shfl_down(pv, o, 64); }
    if (l == 0) { u[j] = pu; vv[j] = pv; }
  } else if (bid < 10640) {                // s0
    int bt = bid - 10624;
    int d = tid*4;
    float4 a = *(const float4*)(z + (size_t)bt*M_*D_ + d);
    float4 q = *(const float4*)(Wattq + d);
    float p = a.x*q.x + a.y*q.y + a.z*q.z + a.w*q.w;
    for (int o = 32; o; o >>= 1) p += __shfl_down(p, o, 64);
    if ((tid & 63) == 0) ps[tid >> 6] = p;
    __syncthreads();
    if (tid == 0) s0[bt] = ps[0]+ps[1]+ps[2]+ps[3];
  } else {                                 // zprep
    int row = bid - 10640;
    const float* zr = z + (size_t)row*D_;
    int d = tid*4;
    float4 v = *(const float4*)(zr + d);
    float ss = v.x*v.x + v.y*v.y + v.z*v.z + v.w*v.w;
    for (int o = 32; o; o >>= 1) ss += __shfl_down(ss, o, 64);
    if ((tid & 63) == 0) pk[tid >> 6] = ss;
    __syncthreads();
    float s = pk[0]+pk[1]+pk[2]+pk[3];
    float rn = 1.0f / fmaxf(sqrtf(s), 1e-12f);
    *(short4*)(zb + (size_t)row*D_ + d) = make_short4(f2b(v.x), f2b(v.y), f2b(v.z), f2b(v.w));
    float zn[4] = {v.x*rn, v.y*rn, v.z*rn, v.w*rn};
    short hi[4], lo[4];
    #pragma unroll
    for (int j = 0; j < 4; ++j) {
      hi[j] = f2b(zn[j]);
      lo[j] = f2b(zn[j] - b2f(hi[j]));
    }
    *(short4*)(znhi + (size_t)row*D_ + d) = make_short4(hi[0],hi[1],hi[2],hi[3]);
    *(short4*)(znlo + (size_t)row*D_ + d) = make_short4(lo[0],lo[1],lo[2],lo[3]);
  }
}

// wave-per-row: top-8 -> att softmax -> alpha -> kbar(bf16) = sum alpha_k z_k
__global__ __launch_bounds__(256) void k_topk(
    const float* __restrict__ sim, const float* __restrict__ kh,
    const float* __restrict__ s0, const bf16* __restrict__ zb,
    bf16* __restrict__ kbarb)
{
  const int wave = threadIdx.x >> 6, l = threadIdx.x & 63;
  const int r  = blockIdx.x*4 + wave;
  const int bt = r >> 9, m = r & 511;
  const int b  = bt >> 3, t = bt & 7;
  const float* srow = sim + (size_t)bt*M_*NC_ + (size_t)m*NC_;
  const int limit = (t >= 2) ? NC_ : ((t == 1) ? 2*M_ : M_);

  float v[24];
  #pragma unroll
  for (int j = 0; j < 24; ++j) {
    int i = j*64 + l;
    v[j] = (i < limit) ? srow[i] : -INFINITY;
  }

  float selv[KNN]; int seli[KNN];
  #pragma unroll
  for (int k = 0; k < KNN; ++k) {
    float bv = v[0]; int bj = 0;
    #pragma unroll
    for (int j = 1; j < 24; ++j)
      if (v[j] > bv) { bv = v[j]; bj = j; }
    int bi = bj*64 + l;
    #pragma unroll
    for (int o = 1; o < 64; o <<= 1) {
      float ov = __shfl_xor(bv, o, 64);
      int   oi = __shfl_xor(bi, o, 64);
      if (ov > bv || (ov == bv && oi < bi)) { bv = ov; bi = oi; }
    }
    selv[k] = bv; seli[k] = bi;
    if ((bi & 63) == l) {
      int jj = bi >> 6;
      #pragma unroll
      for (int j = 0; j < 24; ++j) if (j == jj) v[j] = -INFINITY;
    }
  }

  float khv = 0.f;
  if (l < KNN) {
    int idx = seli[l];
    int w = idx >> 9, n = idx & 511;
    int tt = t - w;
    khv = kh[(b*T_ + tt)*M_ + n];
  }
  float s0v = s0[bt];
  float att[KNN], mx = -INFINITY;
  #pragma unroll
  for (int k = 0; k < KNN; ++k) { att[k] = s0v * __shfl(khv, k, 64); mx = fmaxf(mx, att[k]); }
  float den = 0.f;
  #pragma unroll
  for (int k = 0; k < KNN; ++k) { att[k] = expf(att[k]-mx); den += att[k]; }
  float rden = 1.0f/den;
  float alpha[KNN];
  #pragma unroll
  for (int k = 0; k < KNN; ++k) alpha[k] = 0.5f*selv[k] + 0.5f*att[k]*rden;

  const int d0 = l*16;
  float o[16];
  #pragma unroll
  for (int e = 0; e < 16; ++e) o[e] = 0.f;
  #pragma unroll
  for (int k = 0; k < KNN; ++k) {
    int idx = seli[k];
    int w = idx >> 9, n = idx & 511;
    int tt = t - w;
    const bf16* zp = zb + ((size_t)((b*T_ + tt)*M_ + n))*D_ + d0;
    v8s z0 = *(const v8s*)zp;
    v8s z1 = *(const v8s*)(zp + 8);
    float al = alpha[k];
    #pragma unroll
    for (int e = 0; e < 8; ++e) {
      o[e]   = fmaf(al, b2f(z0[e]), o[e]);
      o[8+e] = fmaf(al, b2f(z1[e]), o[8+e]);
    }
  }
  bf16* kp = kbarb + (size_t)r*D_ + d0;
  short outv[16];
  #pragma unroll
  for (int e = 0; e < 16; ++e) outv[e] = f2b(o[e]);
  *(v8s*)kp       = *(v8s*)outv;
  *(v8s*)(kp + 8) = *(v8s*)(outv + 8);
}

extern "C" void kernel_launch(void* const* d_in, const int* in_sizes, int n_in,
                              void* d_out, int out_size, void* d_ws, size_t ws_size,
                              hipStream_t stream) {
  (void)in_sizes; (void)n_in; (void)out_size; (void)ws_size;
  const float* z      = (const float*)d_in[0];
  const float* Wq     = (const float*)d_in[1];
  const float* Wv     = (const float*)d_in[2];
  const float* Wout   = (const float*)d_in[3];
  const float* ln_w   = (const float*)d_in[4];
  const float* ln_b   = (const float*)d_in[5];
  const float* Watt_q = (const float*)d_in[6];
  const float* Watt_k = (const float*)d_in[7];
  const float* W_ih   = (const float*)d_in[8];
  const float* W_hh   = (const float*)d_in[9];
  const float* b_ih   = (const float*)d_in[10];
  const float* b_hh   = (const float*)d_in[11];
  const float* W_mf   = (const float*)d_in[12];
  const float* b_mf   = (const float*)d_in[13];
  float* out = (float*)d_out;
  float* ws  = (float*)d_ws;

  // workspace layout (float offsets)
  float* sim   = ws;                          // 12,582,912 f ; GIb aliases
  bf16*  GIb   = (bf16*)ws;
  bf16*  znhi  = (bf16*)(ws + 12582912);      // 8,388,608 bf16 ; Xb aliases
  bf16*  Xb    = znhi;
  bf16*  zb    = (bf16*)(ws + 16777216);      // 8,388,608 bf16
  bf16*  kbarb = (bf16*)(ws + 20971520);      // 8,388,608 bf16 ; INPb aliases
  bf16*  INPb  = kbarb;
  bf16*  memhb = (bf16*)(ws + 25165824);      // 8,388,608 bf16 ; znlo aliases
  bf16*  znlo  = memhb;
  bf16*  mA    = (bf16*)(ws + 29360128);      // 1,048,576 bf16
  bf16*  mB    = (bf16*)(ws + 29884416);      // 1,048,576 bf16
  float* mem   = ws + 30408704;               // 1,048,576 f (fp32 GRU state)
  bf16*  Wqb   = (bf16*)(ws + 31457280);      // 10,485,760 bf16 contiguous
  bf16*  Wvb   = Wqb + 1048576;
  bf16*  Woutb = Wqb + 2097152;               // scaled by ln_w
  bf16*  Wihb  = Wqb + 3145728;
  bf16*  Whhb  = Wqb + 6291456;
  bf16*  Wmfb  = Wqb + 9437184;
  float* wks   = ws + 36700160;               // 1024
  float* s0    = ws + 36701184;               // 16
  float* kh    = ws + 36701200;               // 8192
  float* u     = ws + 36709392;               // 1024
  float* vv    = ws + 36710416;               // 1024
  float* ssum  = ws + 36711440;               // 16*8192
  float* ssq   = ws + 36842512;               // 16*8192
  // end 36,973,584 floats ~ 141 MiB

  // 1. zero wks (colsum accumulates via atomics)
  hipMemsetAsync(wks, 0, 1024*sizeof(float), stream);

  // 2. mega-prep
  k_prep<<<dim3(18832), dim3(256), 0, stream>>>(
      Wq, Wv, Wout, W_ih, W_hh, W_mf, ln_w, ln_b, Watt_k, Watt_q, z,
      Wqb, wks, u, vv, s0, zb, znhi, znlo);

  // 3. sim (split-bf16 MFMA) + kh role
  k_sims<<<dim3(4,4,176), dim3(256), 0, stream>>>(znhi, znlo, z, wks, sim, kh);

  // 4. topk + attention + kbar
  k_topk<<<dim3(2048), dim3(256), 0, stream>>>(sim, kh, s0, zb, kbarb);

  // 5. X = kbar@Wv^T + z@Wq^T -> bf16 Xb + LN stats partials
  k_bgemm<true,false,false,true,true><<<dim3(8,64), dim3(256), 0, stream>>>(
      kbarb, Wvb, zb, Wqb, nullptr, nullptr, Xb, D_, D_, ssum, ssq);

  // 6. INP = LN(X)@Wout^T (LN folded) -> bf16
  k_inp<<<dim3(8,64), dim3(256), 0, stream>>>(Xb, Woutb, ssum, ssq, u, vv, INPb);

  // 7. GI = INP@W_ih^T + b_ih -> bf16 (overlays sim)
  k_bgemm<false,true,false,true,false><<<dim3(24,64), dim3(256), 0, stream>>>(
      INPb, Wihb, nullptr, nullptr, b_ih, nullptr, GIb, 3*H_, D_, nullptr, nullptr);

  // 8. 8 per-step fused Whh-GEMM + GRU dispatches (launch boundary = barrier)
  for (int t = 0; t < T_; ++t) {
    bf16*       mout = (t & 1) ? mB : mA;   // write W(t)
    const bf16* min_ = (t & 1) ? mA : mB;   // read  W(t-1); unread at t=0
    k_fgru2<<<dim3(16,16), dim3(256), 0, stream>>>(
        min_, Whhb, GIb, b_hh, mem, mout, memhb,
        out + (size_t)B_*T_*M_*D_, t);
  }

  // 9. OUT = z + memh@W_mf^T + b_mf
  k_bgemm<false,true,true,false,false><<<dim3(8,64), dim3(256), 0, stream>>>(
      memhb, Wmfb, nullptr, nullptr, b_mf, z, out, D_, H_, nullptr, nullptr);
}